// Round 12
// baseline (142.946 us; speedup 1.0000x reference)
//
#include <hip/hip_runtime.h>

#define NNODES 8192
#define KZ 20
#define QB 4      // queries per block
#define SCAP 192  // survivor cap per query; E[n]~45, bounds-guarded

// freqs[j] = 50^(-j/10)
static constexpr float FREQS[10] = {
  1.0f, 0.67624323f, 0.45730491f, 0.30924935f, 0.20912778f,
  0.14142136f, 0.09563524f, 0.06467268f, 0.04373443f, 0.02957512f};

// output offsets (floats)
#define O_XNE  0
#define O_POS  2621440
#define O_NBP  2646016
#define O_NBD  3137536
#define O_EDGE 6414336
#define O_FE   6578176

typedef __attribute__((ext_vector_type(8))) short bfrag;   // 8 bf16 (4 VGPRs)
typedef __attribute__((ext_vector_type(4))) float f32x4;   // MFMA C/D

static __device__ __forceinline__ unsigned short f2bf(float f) {
  unsigned int u = __float_as_uint(f);
  u += 0x7fffu + ((u >> 16) & 1u);
  return (unsigned short)(u >> 16);
}
// wave64 max-reduce via DPP (verified pattern since R6), broadcast to all lanes.
static __device__ __forceinline__ float wave_max_f32(float v) {
  float t;
  t = __builtin_bit_cast(float, __builtin_amdgcn_update_dpp(__builtin_bit_cast(int, v), __builtin_bit_cast(int, v), 0x111, 0xF, 0xF, false)); v = fmaxf(v, t); // row_shr:1
  t = __builtin_bit_cast(float, __builtin_amdgcn_update_dpp(__builtin_bit_cast(int, v), __builtin_bit_cast(int, v), 0x112, 0xF, 0xF, false)); v = fmaxf(v, t); // row_shr:2
  t = __builtin_bit_cast(float, __builtin_amdgcn_update_dpp(__builtin_bit_cast(int, v), __builtin_bit_cast(int, v), 0x114, 0xF, 0xF, false)); v = fmaxf(v, t); // row_shr:4
  t = __builtin_bit_cast(float, __builtin_amdgcn_update_dpp(__builtin_bit_cast(int, v), __builtin_bit_cast(int, v), 0x118, 0xF, 0xF, false)); v = fmaxf(v, t); // row_shr:8
  t = __builtin_bit_cast(float, __builtin_amdgcn_update_dpp(__builtin_bit_cast(int, v), __builtin_bit_cast(int, v), 0x142, 0xF, 0xF, false)); v = fmaxf(v, t); // row_bcast:15
  t = __builtin_bit_cast(float, __builtin_amdgcn_update_dpp(__builtin_bit_cast(int, v), __builtin_bit_cast(int, v), 0x143, 0xF, 0xF, false)); v = fmaxf(v, t); // row_bcast:31
  return __builtin_bit_cast(float, __builtin_amdgcn_readlane(__builtin_bit_cast(int, v), 63));
}

// ---------------- fused prep + x copy + Wt bf16 cast (UNCHANGED R8) ----------------
__global__ __launch_bounds__(256) void k_pre(const float4* __restrict__ x4,
                                             const float* __restrict__ affines,
                                             const int* __restrict__ prot_mask,
                                             const float* __restrict__ lit,
                                             const float* __restrict__ w,
                                             float* __restrict__ out,
                                             float4* __restrict__ pos4,
                                             float4* __restrict__ ncac4,
                                             unsigned short* __restrict__ wtb) {
  int t = blockIdx.x * 256 + threadIdx.x;  // < 655360
  if (t < 524288) {  // copy x into x_ne rows (embedding cols written by gemm)
    int n = t >> 6, c = t & 63;
    ((float4*)out)[n * 80 + c] = x4[t];
  } else {  // bf16 cast of ne_weight -> wtb[64][2048] (K-contiguous, zero pad)
    int u = t - 524288;  // < 131072
    int o = u >> 11, k = u & 2047;
    wtb[u] = (k < 2000) ? f2bf(w[(size_t)o * 2000 + k]) : (unsigned short)0;
  }
  if (t < NNODES) {  // prep: positions, n2, ncac
    int n = t;
    const float4* af = (const float4*)affines + (size_t)n * 3;
    float4 a0 = af[0], a1 = af[1], a2 = af[2];  // rows of rot, .w = trans
    float tx = a0.w, ty = a1.w, tz = a2.w;
    float n2;
    {
#pragma clang fp contract(off)
      // np: sum(pos*pos,-1) = ((x*x + y*y) + z*z), each op rounded, NO fma
      float xx = tx * tx;
      float yy = ty * ty;
      float zz = tz * tz;
      n2 = (xx + yy) + zz;
    }
    pos4[n] = make_float4(tx, ty, tz, n2);
    out[O_POS + n * 3 + 0] = tx;
    out[O_POS + n * 3 + 1] = ty;
    out[O_POS + n * 3 + 2] = tz;
    int aat = (prot_mask[n] != 0) ? 0 : 20;
    const float* lp = lit + aat * 9;
#pragma unroll
    for (int a = 0; a < 3; a++) {
      float l0 = lp[a * 3 + 0], l1 = lp[a * 3 + 1], l2 = lp[a * 3 + 2];
      // ncac[a][i] = sum_j rot[i][j]*lit[a][j] + trans[i]
      float x = a0.x * l0 + a0.y * l1 + a0.z * l2 + tx;
      float y = a1.x * l0 + a1.y * l1 + a1.z * l2 + ty;
      float z = a2.x * l0 + a2.y * l1 + a2.z * l2 + tz;
      ncac4[n * 3 + a] = make_float4(x, y, z, 0.f);
    }
  }
}

// ---------------- fused KNN + gather: Q=4/block, fast-filter + exact keys ----------------
// Filter metric (both passes, IDENTICAL expression -> deterministic):
//   d2~ = fma(-2qx,px, fma(-2qy,py, fma(-2qz,pz, qw+pw)))
// |d2~ - d2exact| <= ~3e-5 (mags<=60, 4 roundings); margin 2*1e-3 is 33x safe.
// Pivot = 21st-smallest of 64 partition minima of d2~ (+margin) => survivors
// (d2~ <= piv_f, c != self) form a superset of the exact top-20.
// Survivor keys use the EXACT canonical arithmetic (bit-identical to all
// passing rounds): dot = fmaf(z,z',fmaf(y,y',x*x')); d2 = (n2i+n2j) - 2*dot.
// Final: exact u64 (key<<13|idx) rank-select (ascending (d2,idx), top_k ties).
__global__ __launch_bounds__(256) void k_knng(const float4* __restrict__ pos4,
                                              const float* __restrict__ affines,
                                              const float4* __restrict__ ncac4,
                                              float* __restrict__ out,
                                              unsigned short* __restrict__ enc) {
  __shared__ float minb[QB][256];              // per-thread minima (4 KB)
  __shared__ float mca[QB][64];                // 128-cand partition minima
  __shared__ float pivots[QB];
  __shared__ unsigned int cnt[QB];
  __shared__ unsigned long long surv[QB][SCAP];  // 6 KB
  __shared__ int nidx[QB][KZ];
  __shared__ float distbuf[QB][100];
  int tid = threadIdx.x;
  int lane = tid & 63, w = tid >> 6;
  int qbase = blockIdx.x * QB;
  // query positions (wave-uniform)
  float4 q0 = pos4[qbase + 0], q1 = pos4[qbase + 1];
  float4 q2 = pos4[qbase + 2], q3 = pos4[qbase + 3];
  // -2*q exact (power-of-2 scale)
  float ax0 = -2.0f * q0.x, ay0 = -2.0f * q0.y, az0 = -2.0f * q0.z;
  float ax1 = -2.0f * q1.x, ay1 = -2.0f * q1.y, az1 = -2.0f * q1.z;
  float ax2 = -2.0f * q2.x, ay2 = -2.0f * q2.y, az2 = -2.0f * q2.z;
  float ax3 = -2.0f * q3.x, ay3 = -2.0f * q3.y, az3 = -2.0f * q3.z;
  const float4* pp = pos4 + tid;
  float l0 = __builtin_inff(), l1 = l0, l2 = l0, l3 = l0;
  {  // ---- pass 1: d2~ minima only ----
#pragma unroll
    for (int s = 0; s < 32; s++) {
      float4 pc = pp[s << 8];
      float d0 = fmaf(ax0, pc.x, fmaf(ay0, pc.y, fmaf(az0, pc.z, q0.w + pc.w)));
      float d1 = fmaf(ax1, pc.x, fmaf(ay1, pc.y, fmaf(az1, pc.z, q1.w + pc.w)));
      float d2 = fmaf(ax2, pc.x, fmaf(ay2, pc.y, fmaf(az2, pc.z, q2.w + pc.w)));
      float d3 = fmaf(ax3, pc.x, fmaf(ay3, pc.y, fmaf(az3, pc.z, q3.w + pc.w)));
      l0 = fminf(l0, d0); l1 = fminf(l1, d1);
      l2 = fminf(l2, d2); l3 = fminf(l3, d3);
    }
  }
  minb[0][tid] = l0; minb[1][tid] = l1; minb[2][tid] = l2; minb[3][tid] = l3;
  __syncthreads();
  {  // ---- pivot: wave w handles query w; +2e-3 soundness margin ----
    float m = fminf(fminf(minb[w][lane], minb[w][lane + 64]),
                    fminf(minb[w][lane + 128], minb[w][lane + 192]));
    mca[w][lane] = m;
    __builtin_amdgcn_s_waitcnt(0);
    __builtin_amdgcn_wave_barrier();
    int c = 0;
#pragma unroll 8
    for (int j = 0; j < 64; j++) c += (mca[w][j] < m) ? 1 : 0;
    float elig = (c < KZ + 1) ? m : -__builtin_inff();
    float piv = wave_max_f32(elig);
    if (lane == 0) { pivots[w] = piv + 2.0e-3f; cnt[w] = 0u; }
  }
  __syncthreads();
  float p0 = pivots[0], p1 = pivots[1], p2 = pivots[2], p3 = pivots[3];
  {  // ---- pass 2: d2~ filter; exact key only for survivors ----
#pragma clang fp contract(off)
#pragma unroll 8
    for (int s = 0; s < 32; s++) {
      float4 pc = pp[s << 8];
      float d0 = fmaf(ax0, pc.x, fmaf(ay0, pc.y, fmaf(az0, pc.z, q0.w + pc.w)));
      float d1 = fmaf(ax1, pc.x, fmaf(ay1, pc.y, fmaf(az1, pc.z, q1.w + pc.w)));
      float d2 = fmaf(ax2, pc.x, fmaf(ay2, pc.y, fmaf(az2, pc.z, q2.w + pc.w)));
      float d3 = fmaf(ax3, pc.x, fmaf(ay3, pc.y, fmaf(az3, pc.z, q3.w + pc.w)));
      int cc = (s << 8) + tid;
      float dv[QB] = {d0, d1, d2, d3};
#pragma unroll
      for (int q = 0; q < QB; q++) {
        float pv = (q == 0) ? p0 : (q == 1) ? p1 : (q == 2) ? p2 : p3;
        if (dv[q] <= pv && cc != qbase + q) {
          // exact canonical d2 (bit-identical to all passing rounds)
          float4 qq = (q == 0) ? q0 : (q == 1) ? q1 : (q == 2) ? q2 : q3;
          float dot = fmaf(qq.z, pc.z, fmaf(qq.y, pc.y, qq.x * pc.x));
          float ex = (qq.w + pc.w) - 2.0f * dot;
          unsigned int b = __float_as_uint(ex);
          unsigned int k = (b & 0x80000000u) ? ~b : (b | 0x80000000u);
          unsigned int ix = atomicAdd(&cnt[q], 1u);
          if (ix < SCAP)  // guard (never hit for this data)
            surv[q][ix] = ((unsigned long long)k << 13) | (unsigned int)cc;
        }
      }
    }
  }
  __syncthreads();
  {  // ---- exact rank-select: wave w handles query w ----
    unsigned int n = cnt[w]; if (n > SCAP) n = SCAP;
    int qi = qbase + w;
    for (unsigned int j = lane; j < n; j += 64) {
      unsigned long long my = surv[w][j];
      int rank = 0;
      for (unsigned int t = 0; t < n; t++) rank += (surv[w][t] < my) ? 1 : 0;
      if (rank < KZ) {
        int idx = (int)(my & 0x1FFFull);
        nidx[w][rank] = idx;
        float fi = (float)idx;
        out[O_EDGE + qi * KZ + rank] = fi;                   // edge_index
        out[O_FE + qi * KZ + rank] = fi;                     // full_edge row0
        out[O_FE + NNODES * KZ + qi * KZ + rank] = (float)qi;  // full_edge row1
      }
    }
  }
  __syncthreads();
  // ---- gather tail: wave w serves query w, lanes 0..19 ----
  int qi = qbase + w;
  if (lane < KZ) {
    const float4* af = (const float4*)affines + (size_t)qi * 3;
    float4 a0 = af[0], a1 = af[1], a2 = af[2];
    float tx = a0.w, ty = a1.w, tz = a2.w;
    int idx = nidx[w][lane];
    float4 p = pos4[idx];
    float bx = p.x - tx, by = p.y - ty, bz = p.z - tz;
    // einsum('nji,nkj->nki'): v_i = sum_j rot[j][i]*b_j (rot^T; NOT orthogonal)
    float vx = a0.x * bx + a1.x * by + a2.x * bz;
    float vy = a0.y * bx + a1.y * by + a2.y * bz;
    float vz = a0.z * bx + a1.z * by + a2.z * bz;
    out[O_NBP + qi * 60 + lane * 3 + 0] = vx;
    out[O_NBP + qi * 60 + lane * 3 + 1] = vy;
    out[O_NBP + qi * 60 + lane * 3 + 2] = vz;
    float dn = sqrtf(vx * vx + vy * vy + vz * vz);
#pragma unroll
    for (int j = 0; j < 10; j++) {
      float a = dn * FREQS[j];
      out[O_NBD + qi * 400 + lane * 20 + j] = __sinf(a);
      out[O_NBD + qi * 400 + lane * 20 + 10 + j] = __cosf(a);
    }
    float4 cn = ncac4[(size_t)qi * 3 + 0];   // n_pos
    float4 ca = ncac4[(size_t)qi * 3 + 1];   // ca_pos
    float4 cc = ncac4[(size_t)qi * 3 + 2];   // c_pos
    float4 nb0 = ncac4[(size_t)idx * 3 + 0];
    float4 nb1 = ncac4[(size_t)idx * 3 + 1];
    float4 nb2 = ncac4[(size_t)idx * 3 + 2];
    auto dist = [](float4 a, float4 b) {
      float dx = a.x - b.x, dy = a.y - b.y, dz = a.z - b.z;
      return sqrtf(dx * dx + dy * dy + dz * dz);
    };
    distbuf[w][lane * 3 + 0] = dist(nb0, ca);
    distbuf[w][lane * 3 + 1] = dist(nb1, ca);
    distbuf[w][lane * 3 + 2] = dist(nb2, ca);
    distbuf[w][60 + lane] = dist(nb2, cn);  // n_to_c
    distbuf[w][80 + lane] = dist(nb0, cc);  // c_to_n
  }
  __syncthreads();
  // ---- enc encode (bf16): 4 rows x 100 cols over 256 threads ----
  for (int u = tid; u < QB * 100; u += 256) {
    int q = u / 100, col = u - q * 100;
    float d = distbuf[q][col];
    unsigned short sh[20];
#pragma unroll
    for (int j = 0; j < 10; j++) {
      float a = d * FREQS[j];
      sh[j] = f2bf(__sinf(a));
      sh[10 + j] = f2bf(__cosf(a));
    }
    unsigned int* dst = (unsigned int*)(enc + (size_t)(qbase + q) * 2048 + col * 20);
#pragma unroll
    for (int wq = 0; wq < 10; wq++)
      dst[wq] = (unsigned int)sh[2 * wq] | ((unsigned int)sh[2 * wq + 1] << 16);
  }
  if (tid < QB * 24) {  // zero K-pad [2000,2048) per row
    int q = tid / 24, wd = tid - q * 24;
    ((unsigned int*)(enc + (size_t)(qbase + q) * 2048 + 2000))[wd] = 0u;
  }
}

// ---------------- MFMA GEMM (UNCHANGED R8) ----------------
__global__ __launch_bounds__(256) void k_gemm(const unsigned short* __restrict__ enc,
                                              const unsigned short* __restrict__ wtb,
                                              float* __restrict__ out) {
  __shared__ float red[4][16][68];  // +4 pad: conflict-free, 16B-aligned rows
  int tid = threadIdx.x;
  int w = tid >> 6, lane = tid & 63;
  int m0 = blockIdx.x * 16;
  int am = lane & 15, ak = (lane >> 4) * 8;
  const unsigned short* arow = enc + (size_t)(m0 + am) * 2048 + w * 512 + ak;
  const unsigned short* brow = wtb + (size_t)am * 2048 + w * 512 + ak;
  f32x4 acc0 = {0.f, 0.f, 0.f, 0.f}, acc1 = acc0, acc2 = acc0, acc3 = acc0;
#pragma unroll 4
  for (int ks = 0; ks < 16; ks++) {
    bfrag a = *(const bfrag*)(arow + ks * 32);
    bfrag b0 = *(const bfrag*)(brow + ks * 32);
    bfrag b1 = *(const bfrag*)(brow + 16 * 2048 + ks * 32);
    bfrag b2 = *(const bfrag*)(brow + 32 * 2048 + ks * 32);
    bfrag b3 = *(const bfrag*)(brow + 48 * 2048 + ks * 32);
    acc0 = __builtin_amdgcn_mfma_f32_16x16x32_bf16(a, b0, acc0, 0, 0, 0);
    acc1 = __builtin_amdgcn_mfma_f32_16x16x32_bf16(a, b1, acc1, 0, 0, 0);
    acc2 = __builtin_amdgcn_mfma_f32_16x16x32_bf16(a, b2, acc2, 0, 0, 0);
    acc3 = __builtin_amdgcn_mfma_f32_16x16x32_bf16(a, b3, acc3, 0, 0, 0);
  }
  {  // write partials: row=(lane>>4)*4+r, col=lane&15 (+16 per nt)
    int rm = (lane >> 4) * 4, cn = lane & 15;
#pragma unroll
    for (int r = 0; r < 4; r++) {
      red[w][rm + r][cn +  0] = acc0[r];
      red[w][rm + r][cn + 16] = acc1[r];
      red[w][rm + r][cn + 32] = acc2[r];
      red[w][rm + r][cn + 48] = acc3[r];
    }
  }
  __syncthreads();
  // reduce 4 partials; 256 threads x one float4 = 16 rows x 64 cols
  int m = tid >> 4, n = (tid & 15) * 4;
  float4 s0 = *(const float4*)&red[0][m][n];
  float4 s1 = *(const float4*)&red[1][m][n];
  float4 s2 = *(const float4*)&red[2][m][n];
  float4 s3 = *(const float4*)&red[3][m][n];
  float4 s = make_float4(s0.x + s1.x + s2.x + s3.x, s0.y + s1.y + s2.y + s3.y,
                         s0.z + s1.z + s2.z + s3.z, s0.w + s1.w + s2.w + s3.w);
  *(float4*)&out[(size_t)(m0 + m) * 320 + 256 + n] = s;
}

extern "C" void kernel_launch(void* const* d_in, const int* in_sizes, int n_in,
                              void* d_out, int out_size, void* d_ws, size_t ws_size,
                              hipStream_t stream) {
  const float* x = (const float*)d_in[0];
  const float* affines = (const float*)d_in[1];
  const float* ne_w = (const float*)d_in[2];
  const float* lit = (const float*)d_in[3];
  const int* mask = (const int*)d_in[4];
  float* out = (float*)d_out;
  char* ws = (char*)d_ws;
  // ws layout (bytes)
  float4* pos4 = (float4*)(ws + 0);                   //  8192*16   = 131072
  float4* ncac4 = (float4*)(ws + 131072);             //  8192*48   -> 524288
  unsigned short* wtb = (unsigned short*)(ws + 524288);   // 64*2048*2 -> 786432
  unsigned short* enc = (unsigned short*)(ws + 1703936);  // 8192*2048*2 -> 35258368

  k_pre<<<2560, 256, 0, stream>>>((const float4*)x, affines, mask, lit, ne_w,
                                  out, pos4, ncac4, wtb);
  k_knng<<<NNODES / QB, 256, 0, stream>>>(pos4, affines, ncac4, out, enc);
  k_gemm<<<512, 256, 0, stream>>>(enc, wtb, out);
}